// Round 1
// baseline (1637.790 us; speedup 1.0000x reference)
//
#include <hip/hip_runtime.h>
#include <stdint.h>

#define SEQ 2048
#define DM 4096
#define NHEADS 16
#define DHEAD 256
#define DFF 16384

typedef __attribute__((ext_vector_type(8))) short short8;
typedef __attribute__((ext_vector_type(4))) float f32x4;
typedef __attribute__((ext_vector_type(4))) float float4v;
typedef __attribute__((ext_vector_type(4))) unsigned short ushort4v;
typedef __attribute__((ext_vector_type(8))) unsigned short ushort8v;

__device__ __forceinline__ unsigned short f2b(float f) {
    uint32_t u = __builtin_bit_cast(uint32_t, f);
    u = (u + 0x7FFFu + ((u >> 16) & 1u)) >> 16;
    return (unsigned short)u;
}

__device__ __forceinline__ void gload_lds16(const void* g, void* l) {
    __builtin_amdgcn_global_load_lds((const __attribute__((address_space(1))) void*)g,
                                     (__attribute__((address_space(3))) void*)l, 16, 0, 0);
}

// ---------------- transpose + (optional f32->bf16) convert ----------------
// src logical [R][C] with row stride ldS -> dst bf16 [C][R] with row stride ldD
template <typename T>
__global__ __launch_bounds__(256) void transpose_cvt(const T* __restrict__ src,
                                                     unsigned short* __restrict__ dst,
                                                     int ldS, int ldD, int R, int C) {
    __shared__ unsigned short tl[64 * 66];
    int r0 = blockIdx.y << 6, c0 = blockIdx.x << 6;
    int tid = threadIdx.x;
#pragma unroll
    for (int it = 0; it < 4; ++it) {
        int e = (tid + it * 256) * 4;
        int rr = e >> 6, cc = e & 63;
        const T* sp = src + (size_t)(r0 + rr) * ldS + c0 + cc;
        if constexpr (sizeof(T) == 4) {
            float4v v = *(const float4v*)sp;
#pragma unroll
            for (int j = 0; j < 4; ++j) tl[rr * 66 + cc + j] = f2b(v[j]);
        } else {
            ushort4v v = *(const ushort4v*)sp;
#pragma unroll
            for (int j = 0; j < 4; ++j) tl[rr * 66 + cc + j] = v[j];
        }
    }
    __syncthreads();
#pragma unroll
    for (int it = 0; it < 2; ++it) {
        int e = tid + it * 256;
        int oc = e >> 3;
        int k8 = (e & 7) * 8;
        ushort8v w;
#pragma unroll
        for (int j = 0; j < 8; ++j) w[j] = tl[(k8 + j) * 66 + oc];
        *(ushort8v*)(dst + (size_t)(c0 + oc) * ldD + r0 + k8) = w;
    }
}

// ---------------- LayerNorm: f32 [SEQ][DM] -> bf16 ----------------
__global__ __launch_bounds__(256) void ln_kernel(const float* __restrict__ x,
                                                 const float* __restrict__ sc,
                                                 const float* __restrict__ of,
                                                 unsigned short* __restrict__ h) {
    int row = blockIdx.x;
    int tid = threadIdx.x, lane = tid & 63, wave = tid >> 6;
    const float4v* xr = (const float4v*)(x + (size_t)row * DM);
    float4v v[4];
    float s = 0.f, s2 = 0.f;
#pragma unroll
    for (int i = 0; i < 4; ++i) {
        v[i] = xr[tid + i * 256];
#pragma unroll
        for (int j = 0; j < 4; ++j) { s += v[i][j]; s2 += v[i][j] * v[i][j]; }
    }
#pragma unroll
    for (int o = 1; o < 64; o <<= 1) { s += __shfl_xor(s, o); s2 += __shfl_xor(s2, o); }
    __shared__ float rs[4], rs2[4];
    if (lane == 0) { rs[wave] = s; rs2[wave] = s2; }
    __syncthreads();
    s = rs[0] + rs[1] + rs[2] + rs[3];
    s2 = rs2[0] + rs2[1] + rs2[2] + rs2[3];
    float mean = s * (1.0f / DM);
    float var = s2 * (1.0f / DM) - mean * mean;
    float inv = rsqrtf(var + 1e-5f);
#pragma unroll
    for (int i = 0; i < 4; ++i) {
        int c = (tid + i * 256) * 4;
        ushort4v o4;
#pragma unroll
        for (int j = 0; j < 4; ++j)
            o4[j] = f2b((v[i][j] - mean) * inv * sc[c + j] + of[c + j]);
        *(ushort4v*)(h + (size_t)row * DM + c) = o4;
    }
}

// ---------------- GEMM: C[M,N] = A[M,K](bf16) * BT[N,K]^T (bf16) ----------------
// EPI: 0 = bf16 store, 1 = f32 store, 2 = +bias, gelu, bf16 store, 3 = +bias +addm, f32 store
template <int EPI>
__global__ __launch_bounds__(256, 2) void gemm_bt(const unsigned short* __restrict__ A,
                                                  const unsigned short* __restrict__ BT,
                                                  void* __restrict__ Cout,
                                                  int M, int N, int K, int ldc,
                                                  const float* __restrict__ bias,
                                                  const float* __restrict__ addm) {
    __shared__ unsigned short aL[128 * 32];
    __shared__ unsigned short bL[128 * 32];

    int nbx = N >> 7;
    int nwg = (M >> 7) * nbx;
    int wg = blockIdx.x;
    if ((nwg & 7) == 0) wg = (wg & 7) * (nwg >> 3) + (wg >> 3);  // XCD swizzle
    int by = wg / nbx, bx = wg % nbx;

    int tid = threadIdx.x, lane = tid & 63, wave = tid >> 6;
    int wm = wave >> 1, wn = wave & 1;

    size_t loff = (size_t)(lane >> 2) * K + ((lane & 3) << 3);
    const unsigned short* gA0 = A + (size_t)(by * 128 + wave * 32) * K + loff;
    const unsigned short* gA1 = gA0 + (size_t)16 * K;
    const unsigned short* gB0 = BT + (size_t)(bx * 128 + wave * 32) * K + loff;
    const unsigned short* gB1 = gB0 + (size_t)16 * K;
    unsigned short* lA0 = aL + wave * 1024;
    unsigned short* lA1 = lA0 + 512;
    unsigned short* lB0 = bL + wave * 1024;
    unsigned short* lB1 = lB0 + 512;

    f32x4 acc[4][4];
#pragma unroll
    for (int i = 0; i < 4; ++i)
#pragma unroll
        for (int j = 0; j < 4; ++j) acc[i][j] = (f32x4){0.f, 0.f, 0.f, 0.f};

    const unsigned short* aF = aL + (wm * 64 + (lane & 15)) * 32 + ((lane >> 4) << 3);
    const unsigned short* bF = bL + (wn * 64 + (lane & 15)) * 32 + ((lane >> 4) << 3);

    int nk = K >> 5;
    for (int kt = 0; kt < nk; ++kt) {
        int ko = kt << 5;
        gload_lds16(gA0 + ko, lA0);
        gload_lds16(gA1 + ko, lA1);
        gload_lds16(gB0 + ko, lB0);
        gload_lds16(gB1 + ko, lB1);
        __syncthreads();
        short8 a[4], b[4];
#pragma unroll
        for (int i = 0; i < 4; ++i) a[i] = *(const short8*)(aF + i * 16 * 32);
#pragma unroll
        for (int j = 0; j < 4; ++j) b[j] = *(const short8*)(bF + j * 16 * 32);
#pragma unroll
        for (int i = 0; i < 4; ++i)
#pragma unroll
            for (int j = 0; j < 4; ++j)
                acc[i][j] = __builtin_amdgcn_mfma_f32_16x16x32_bf16(a[i], b[j], acc[i][j], 0, 0, 0);
        __syncthreads();
    }

    int r0 = by * 128 + wm * 64;
    int c0 = bx * 128 + wn * 64;
    int rl = (lane >> 4) << 2;
    int cl = lane & 15;
#pragma unroll
    for (int i = 0; i < 4; ++i) {
#pragma unroll
        for (int j = 0; j < 4; ++j) {
            int col = c0 + j * 16 + cl;
#pragma unroll
            for (int r = 0; r < 4; ++r) {
                int row = r0 + i * 16 + rl + r;
                float v = acc[i][j][r];
                if constexpr (EPI == 0) {
                    ((unsigned short*)Cout)[(size_t)row * ldc + col] = f2b(v);
                } else if constexpr (EPI == 1) {
                    ((float*)Cout)[(size_t)row * ldc + col] = v;
                } else if constexpr (EPI == 2) {
                    v += bias[col];
                    float t = tanhf(0.7978845608f * (v + 0.044715f * v * v * v));
                    ((unsigned short*)Cout)[(size_t)row * ldc + col] = f2b(0.5f * v * (1.0f + t));
                } else {
                    v += bias[col] + addm[(size_t)row * ldc + col];
                    ((float*)Cout)[(size_t)row * ldc + col] = v;
                }
            }
        }
    }
}

// ---------------- flash attention ----------------
// qkv: bf16 [SEQ][3*DM] (q | k | v), vT: bf16 [DM][SEQ], bias f32 [SEQ][SEQ]
// out: attn_vec bf16 [SEQ][DM]
__global__ __launch_bounds__(256, 2) void attn_kernel(const unsigned short* __restrict__ qkv,
                                                      const unsigned short* __restrict__ vT,
                                                      const float* __restrict__ bias,
                                                      unsigned short* __restrict__ attn_vec) {
    __shared__ unsigned short kL[64 * 264];
    __shared__ unsigned short vL[256 * 72];
    __shared__ unsigned short pL[4][16 * 72];

    int qb = blockIdx.x, head = blockIdx.y;
    int tid = threadIdx.x, lane = tid & 63, wave = tid >> 6;
    int q16 = lane & 15, q4 = lane >> 4;

    short8 qf[8];
    {
        const unsigned short* qp =
            qkv + (size_t)(qb * 64 + wave * 16 + q16) * (3 * DM) + head * DHEAD + (q4 << 3);
#pragma unroll
        for (int kk = 0; kk < 8; ++kk) qf[kk] = *(const short8*)(qp + kk * 32);
    }

    f32x4 o[16];
#pragma unroll
    for (int d = 0; d < 16; ++d) o[d] = (f32x4){0.f, 0.f, 0.f, 0.f};
    float m_run[4] = {-INFINITY, -INFINITY, -INFINITY, -INFINITY};
    float l_run[4] = {0.f, 0.f, 0.f, 0.f};
    int qrow0 = qb * 64 + wave * 16 + q4 * 4;

    for (int t = 0; t <= qb; ++t) {
        int kv0 = t * 64;
#pragma unroll
        for (int rr = 0; rr < 8; ++rr) {  // K tile [64][256] -> kL[64][264]
            int i = tid + rr * 256;
            int row = i >> 5, c8 = (i & 31) << 3;
            *(ushort8v*)(kL + row * 264 + c8) =
                *(const ushort8v*)(qkv + (size_t)(kv0 + row) * (3 * DM) + DM + head * DHEAD + c8);
        }
#pragma unroll
        for (int rr = 0; rr < 8; ++rr) {  // V^T tile [256][64] -> vL[256][72]
            int i = tid + rr * 256;
            int d = i >> 3, c8 = (i & 7) << 3;
            *(ushort8v*)(vL + d * 72 + c8) =
                *(const ushort8v*)(vT + (size_t)(head * DHEAD + d) * SEQ + kv0 + c8);
        }
        __syncthreads();

        f32x4 s[4];
#pragma unroll
        for (int c = 0; c < 4; ++c) s[c] = (f32x4){0.f, 0.f, 0.f, 0.f};
#pragma unroll
        for (int kk = 0; kk < 8; ++kk) {
#pragma unroll
            for (int c = 0; c < 4; ++c) {
                short8 kf = *(const short8*)(kL + (c * 16 + q16) * 264 + kk * 32 + (q4 << 3));
                s[c] = __builtin_amdgcn_mfma_f32_16x16x32_bf16(qf[kk], kf, s[c], 0, 0, 0);
            }
        }

        bool diag = (t == qb);
#pragma unroll
        for (int r = 0; r < 4; ++r) {
            int qr = qrow0 + r;
            float sv[4];
#pragma unroll
            for (int c = 0; c < 4; ++c) {
                float vv = s[c][r] * 0.0625f + bias[(size_t)qr * SEQ + kv0 + c * 16 + q16];
                if (diag && (kv0 + c * 16 + q16) > qr) vv = -1e30f;
                sv[c] = vv;
            }
            float m = fmaxf(fmaxf(sv[0], sv[1]), fmaxf(sv[2], sv[3]));
#pragma unroll
            for (int off = 1; off < 16; off <<= 1) m = fmaxf(m, __shfl_xor(m, off));
            float mn = fmaxf(m_run[r], m);
            float alpha = __expf(m_run[r] - mn);
            float psum = 0.f;
#pragma unroll
            for (int c = 0; c < 4; ++c) {
                float p = __expf(sv[c] - mn);
                psum += p;
                pL[wave][(q4 * 4 + r) * 72 + c * 16 + q16] = f2b(p);
            }
#pragma unroll
            for (int off = 1; off < 16; off <<= 1) psum += __shfl_xor(psum, off);
            l_run[r] = l_run[r] * alpha + psum;
            m_run[r] = mn;
#pragma unroll
            for (int d = 0; d < 16; ++d) o[d][r] *= alpha;
        }

#pragma unroll
        for (int ks = 0; ks < 2; ++ks) {
            short8 pa = *(const short8*)(pL[wave] + q16 * 72 + ks * 32 + (q4 << 3));
#pragma unroll
            for (int d = 0; d < 16; ++d) {
                short8 vb = *(const short8*)(vL + (d * 16 + q16) * 72 + ks * 32 + (q4 << 3));
                o[d] = __builtin_amdgcn_mfma_f32_16x16x32_bf16(pa, vb, o[d], 0, 0, 0);
            }
        }
        __syncthreads();
    }

#pragma unroll
    for (int r = 0; r < 4; ++r) {
        float inv = 1.0f / l_run[r];
#pragma unroll
        for (int d = 0; d < 16; ++d)
            attn_vec[(size_t)(qrow0 + r) * DM + head * DHEAD + d * 16 + q16] = f2b(o[d][r] * inv);
    }
}

// ---------------- launch ----------------
extern "C" void kernel_launch(void* const* d_in, const int* in_sizes, int n_in,
                              void* d_out, int out_size, void* d_ws, size_t ws_size,
                              hipStream_t stream) {
    const float* x = (const float*)d_in[0];
    const float* attn_bias = (const float*)d_in[1];
    const float* ln_scale = (const float*)d_in[2];
    const float* ln_offset = (const float*)d_in[3];
    const float* wq = (const float*)d_in[4];
    const float* wk = (const float*)d_in[5];
    const float* wv = (const float*)d_in[6];
    const float* wo = (const float*)d_in[7];
    const float* w_ffn = (const float*)d_in[8];
    const float* b_ffn = (const float*)d_in[9];
    const float* w_ffn_o = (const float*)d_in[10];
    const float* b_ffn_o = (const float*)d_in[11];
    float* out = (float*)d_out;

    char* p = (char*)d_ws;
    unsigned short* WT_qkv = (unsigned short*)p; p += (size_t)3 * DM * DM * 2;   // [12288][4096]
    unsigned short* WT_o = (unsigned short*)p;   p += (size_t)DM * DM * 2;       // [4096][4096]
    unsigned short* WT_f1 = (unsigned short*)p;  p += (size_t)DFF * DM * 2;      // [16384][4096]
    unsigned short* WT_f2 = (unsigned short*)p;  p += (size_t)DM * DFF * 2;      // [4096][16384]
    unsigned short* hB = (unsigned short*)p;     p += (size_t)SEQ * DM * 2;      // [2048][4096]
    unsigned short* qkvB = (unsigned short*)p;   p += (size_t)SEQ * 3 * DM * 2;  // [2048][12288]
    unsigned short* vTB = (unsigned short*)p;    p += (size_t)DM * SEQ * 2;      // [4096][2048]
    unsigned short* avB = (unsigned short*)p;    p += (size_t)SEQ * DM * 2;      // [2048][4096]
    float* attn_out = (float*)p;                 p += (size_t)SEQ * DM * 4;      // [2048][4096] f32
    unsigned short* ffB = (unsigned short*)p;    p += (size_t)SEQ * DFF * 2;     // [2048][16384]

    // weights -> bf16 transposed
    transpose_cvt<float><<<dim3(DM / 64, DM / 64), 256, 0, stream>>>(wq, WT_qkv, DM, DM, DM, DM);
    transpose_cvt<float><<<dim3(DM / 64, DM / 64), 256, 0, stream>>>(wk, WT_qkv + (size_t)DM * DM, DM, DM, DM, DM);
    transpose_cvt<float><<<dim3(DM / 64, DM / 64), 256, 0, stream>>>(wv, WT_qkv + (size_t)2 * DM * DM, DM, DM, DM, DM);
    transpose_cvt<float><<<dim3(DM / 64, DM / 64), 256, 0, stream>>>(wo, WT_o, DM, DM, DM, DM);
    transpose_cvt<float><<<dim3(DFF / 64, DM / 64), 256, 0, stream>>>(w_ffn, WT_f1, DFF, DM, DM, DFF);
    transpose_cvt<float><<<dim3(DM / 64, DFF / 64), 256, 0, stream>>>(w_ffn_o, WT_f2, DM, DFF, DFF, DM);

    ln_kernel<<<SEQ, 256, 0, stream>>>(x, ln_scale, ln_offset, hB);

    // fused QKV
    gemm_bt<0><<<(SEQ / 128) * (3 * DM / 128), 256, 0, stream>>>(hB, WT_qkv, qkvB, SEQ, 3 * DM, DM, 3 * DM, nullptr, nullptr);
    // V slice -> vT [DM][SEQ]
    transpose_cvt<unsigned short><<<dim3(DM / 64, SEQ / 64), 256, 0, stream>>>(qkvB + 2 * DM, vTB, 3 * DM, SEQ, SEQ, DM);

    attn_kernel<<<dim3(SEQ / 64, NHEADS), 256, 0, stream>>>(qkvB, vTB, attn_bias, avB);

    // attn_out = attn_vec @ wo (f32)
    gemm_bt<1><<<(SEQ / 128) * (DM / 128), 256, 0, stream>>>(avB, WT_o, attn_out, SEQ, DM, DM, DM, nullptr, nullptr);
    // ff = gelu(h @ w_ffn + b_ffn) (bf16)
    gemm_bt<2><<<(SEQ / 128) * (DFF / 128), 256, 0, stream>>>(hB, WT_f1, ffB, SEQ, DFF, DM, DFF, b_ffn, nullptr);
    // out = ff @ w_ffn_o + b_ffn_o + attn_out (f32)
    gemm_bt<3><<<(SEQ / 128) * (DM / 128), 256, 0, stream>>>(ffB, WT_f2, out, SEQ, DM, DFF, DM, b_ffn_o, attn_out);
}

// Round 2
// 1610.323 us; speedup vs baseline: 1.0171x; 1.0171x over previous
//
#include <hip/hip_runtime.h>
#include <stdint.h>

#define SEQ 2048
#define DM 4096
#define NHEADS 16
#define DHEAD 256
#define DFF 16384

typedef __attribute__((ext_vector_type(8))) short short8;
typedef __attribute__((ext_vector_type(4))) float f32x4;
typedef __attribute__((ext_vector_type(4))) float float4v;
typedef __attribute__((ext_vector_type(4))) unsigned short ushort4v;
typedef __attribute__((ext_vector_type(8))) unsigned short ushort8v;

__device__ __forceinline__ unsigned short f2b(float f) {
    uint32_t u = __builtin_bit_cast(uint32_t, f);
    u = (u + 0x7FFFu + ((u >> 16) & 1u)) >> 16;
    return (unsigned short)u;
}

__device__ __forceinline__ void gload_lds16(const void* g, void* l) {
    __builtin_amdgcn_global_load_lds((const __attribute__((address_space(1))) void*)g,
                                     (__attribute__((address_space(3))) void*)l, 16, 0, 0);
}

// ---------------- transpose + (optional f32->bf16) convert ----------------
template <typename T>
__global__ __launch_bounds__(256) void transpose_cvt(const T* __restrict__ src,
                                                     unsigned short* __restrict__ dst,
                                                     int ldS, int ldD, int R, int C) {
    __shared__ unsigned short tl[64 * 66];
    int r0 = blockIdx.y << 6, c0 = blockIdx.x << 6;
    int tid = threadIdx.x;
#pragma unroll
    for (int it = 0; it < 4; ++it) {
        int e = (tid + it * 256) * 4;
        int rr = e >> 6, cc = e & 63;
        const T* sp = src + (size_t)(r0 + rr) * ldS + c0 + cc;
        if constexpr (sizeof(T) == 4) {
            float4v v = *(const float4v*)sp;
#pragma unroll
            for (int j = 0; j < 4; ++j) tl[rr * 66 + cc + j] = f2b(v[j]);
        } else {
            ushort4v v = *(const ushort4v*)sp;
#pragma unroll
            for (int j = 0; j < 4; ++j) tl[rr * 66 + cc + j] = v[j];
        }
    }
    __syncthreads();
#pragma unroll
    for (int it = 0; it < 2; ++it) {
        int e = tid + it * 256;
        int oc = e >> 3;
        int k8 = (e & 7) * 8;
        ushort8v w;
#pragma unroll
        for (int j = 0; j < 8; ++j) w[j] = tl[(k8 + j) * 66 + oc];
        *(ushort8v*)(dst + (size_t)(c0 + oc) * ldD + r0 + k8) = w;
    }
}

// ---------------- LayerNorm ----------------
__global__ __launch_bounds__(256) void ln_kernel(const float* __restrict__ x,
                                                 const float* __restrict__ sc,
                                                 const float* __restrict__ of,
                                                 unsigned short* __restrict__ h) {
    int row = blockIdx.x;
    int tid = threadIdx.x, lane = tid & 63, wave = tid >> 6;
    const float4v* xr = (const float4v*)(x + (size_t)row * DM);
    float4v v[4];
    float s = 0.f, s2 = 0.f;
#pragma unroll
    for (int i = 0; i < 4; ++i) {
        v[i] = xr[tid + i * 256];
#pragma unroll
        for (int j = 0; j < 4; ++j) { s += v[i][j]; s2 += v[i][j] * v[i][j]; }
    }
#pragma unroll
    for (int o = 1; o < 64; o <<= 1) { s += __shfl_xor(s, o); s2 += __shfl_xor(s2, o); }
    __shared__ float rs[4], rs2[4];
    if (lane == 0) { rs[wave] = s; rs2[wave] = s2; }
    __syncthreads();
    s = rs[0] + rs[1] + rs[2] + rs[3];
    s2 = rs2[0] + rs2[1] + rs2[2] + rs2[3];
    float mean = s * (1.0f / DM);
    float var = s2 * (1.0f / DM) - mean * mean;
    float inv = rsqrtf(var + 1e-5f);
#pragma unroll
    for (int i = 0; i < 4; ++i) {
        int c = (tid + i * 256) * 4;
        ushort4v o4;
#pragma unroll
        for (int j = 0; j < 4; ++j)
            o4[j] = f2b((v[i][j] - mean) * inv * sc[c + j] + of[c + j]);
        *(ushort4v*)(h + (size_t)row * DM + c) = o4;
    }
}

// ---------------- deep-pipelined GEMM: C[M,N] = A[M,K] * BT[N,K]^T ----------------
// BM=256, BN=128, BK=64, 512 threads (8 waves as 4x2), per-wave 64x64 output.
// A: 2-deep dbuf (64KB), B: 3-deep ring (48KB). XOR-swizzled LDS (row&7)<<4.
// 4 phases per K-tile; counted vmcnt(6); raw barriers; setprio around MFMA.
// EPI: 0=bf16, 1=f32, 2=+bias gelu bf16, 3=+bias+addm f32
#define MF(a, b, c) __builtin_amdgcn_mfma_f32_16x16x32_bf16(a, b, c, 0, 0, 0)

#define PH()                                  \
    __builtin_amdgcn_sched_barrier(0);        \
    __builtin_amdgcn_s_barrier();             \
    __builtin_amdgcn_sched_barrier(0);

#define LDA(D, BUF, R)                                              \
    D[0][0] = *(const short8*)((BUF) + (R) * 64 + ca0);             \
    D[0][1] = *(const short8*)((BUF) + (R) * 64 + ca1);             \
    D[1][0] = *(const short8*)((BUF) + ((R) + 16) * 64 + ca0);      \
    D[1][1] = *(const short8*)((BUF) + ((R) + 16) * 64 + ca1);

#define LDB(D, BUF, R)                                              \
    D[0][0] = *(const short8*)((BUF) + (R) * 64 + cb0);             \
    D[0][1] = *(const short8*)((BUF) + (R) * 64 + cb1);             \
    D[1][0] = *(const short8*)((BUF) + ((R) + 16) * 64 + cb0);      \
    D[1][1] = *(const short8*)((BUF) + ((R) + 16) * 64 + cb1);

#define MFMA8(AQ, BQ, I, J)                                         \
    __builtin_amdgcn_s_setprio(1);                                  \
    acc[I][J] = MF(AQ[0][0], BQ[0][0], acc[I][J]);                  \
    acc[I][J] = MF(AQ[0][1], BQ[0][1], acc[I][J]);                  \
    acc[I][J + 1] = MF(AQ[0][0], BQ[1][0], acc[I][J + 1]);          \
    acc[I][J + 1] = MF(AQ[0][1], BQ[1][1], acc[I][J + 1]);          \
    acc[I + 1][J] = MF(AQ[1][0], BQ[0][0], acc[I + 1][J]);          \
    acc[I + 1][J] = MF(AQ[1][1], BQ[0][1], acc[I + 1][J]);          \
    acc[I + 1][J + 1] = MF(AQ[1][0], BQ[1][0], acc[I + 1][J + 1]);  \
    acc[I + 1][J + 1] = MF(AQ[1][1], BQ[1][1], acc[I + 1][J + 1]);  \
    __builtin_amdgcn_s_setprio(0);

#define VM6 asm volatile("s_waitcnt vmcnt(6)" ::: "memory")
#define VM0 asm volatile("s_waitcnt vmcnt(0)" ::: "memory")

#define KGROUP(DO_STAGE, WAITC)                         \
    {                                                   \
        const unsigned short* aBuf = aL[u & 1];         \
        const unsigned short* bBuf = bL[u % 3];         \
        short8 aQ0[2][2], aQ1[2][2], bQ0[2][2], bQ1[2][2]; \
        if (DO_STAGE) stageB(u + 2);                    \
        LDA(aQ0, aBuf, arow);                           \
        LDB(bQ0, bBuf, brow);                           \
        PH();                                           \
        MFMA8(aQ0, bQ0, 0, 0);                          \
        PH();                                           \
        LDA(aQ1, aBuf, arow + 32);                      \
        PH();                                           \
        MFMA8(aQ1, bQ0, 2, 0);                          \
        PH();                                           \
        if (DO_STAGE) stageA(u + 2, 0);                 \
        LDB(bQ1, bBuf, brow + 32);                      \
        PH();                                           \
        MFMA8(aQ0, bQ1, 0, 2);                          \
        PH();                                           \
        if (DO_STAGE) stageA(u + 2, 1);                 \
        WAITC;                                          \
        PH();                                           \
        MFMA8(aQ1, bQ1, 2, 2);                          \
        PH();                                           \
    }

template <int EPI>
__global__ __launch_bounds__(512, 2) void gemm256(const unsigned short* __restrict__ A,
                                                  const unsigned short* __restrict__ BT,
                                                  void* __restrict__ Cout,
                                                  int M, int N, int K, int ldc,
                                                  const float* __restrict__ bias,
                                                  const float* __restrict__ addm) {
    __shared__ unsigned short aL[2][256 * 64];  // 64 KB
    __shared__ unsigned short bL[3][128 * 64];  // 48 KB

    const int nbx = N >> 7;
    const int nwg = (M >> 8) * nbx;
    int wg = blockIdx.x;
    wg = (wg & 7) * (nwg >> 3) + (wg >> 3);  // XCD swizzle (all grids %8==0)
    const int by = wg / nbx, bx = wg % nbx;
    const int bm0 = by << 8, bn0 = bx << 7;

    const int tid = threadIdx.x, lane = tid & 63, wave = tid >> 6;
    const int wm = wave >> 1, wn = wave & 1;
    const int l15 = lane & 15, kl = lane >> 4;

    // staging precompute: per-thread granule -> (row, swizzled k)
    const int rh = tid >> 3;                             // 0..63 (and +64 for granule 2)
    const int cb_s = (tid & 7) << 4;                     // phys col byte 0..112
    const int kx = (cb_s ^ ((rh & 7) << 4)) >> 1;        // source k element offset

    const unsigned short* Abase = A + (size_t)bm0 * K;
    const unsigned short* Bbase = BT + (size_t)bn0 * K;

    auto stageA = [&](int v, int h) {
        const unsigned short* g = Abase + (size_t)(h * 128 + rh) * K + (size_t)v * 64 + kx;
        char* l = (char*)(aL[v & 1] + h * 8192);
        gload_lds16(g, l + tid * 16);
        gload_lds16(g + (size_t)64 * K, l + 8192 + tid * 16);
    };
    auto stageB = [&](int v) {
        const unsigned short* g = Bbase + (size_t)rh * K + (size_t)v * 64 + kx;
        char* l = (char*)(bL[v % 3]);
        gload_lds16(g, l + tid * 16);
        gload_lds16(g + (size_t)64 * K, l + 8192 + tid * 16);
    };

    // fragment-read precompute (swizzled LDS addresses)
    const int arow = wm * 64 + l15;
    const int brow = wn * 64 + l15;
    const int sa = (arow & 7) << 4;
    const int sb = (brow & 7) << 4;
    const int ca0 = ((kl * 16) ^ sa) >> 1;
    const int ca1 = ((64 + kl * 16) ^ sa) >> 1;
    const int cb0 = ((kl * 16) ^ sb) >> 1;
    const int cb1 = ((64 + kl * 16) ^ sb) >> 1;

    f32x4 acc[4][4];
#pragma unroll
    for (int i = 0; i < 4; ++i)
#pragma unroll
        for (int j = 0; j < 4; ++j) acc[i][j] = (f32x4){0.f, 0.f, 0.f, 0.f};

    const int NT = K >> 6;

    // prologue: tile0 {B,A0,A1}, tile1 {B,A0,A1} -> 12 loads; newest 6 = tile1
    stageB(0); stageA(0, 0); stageA(0, 1);
    stageB(1); stageA(1, 0); stageA(1, 1);
    VM6;
    __builtin_amdgcn_sched_barrier(0);
    __builtin_amdgcn_s_barrier();
    __builtin_amdgcn_sched_barrier(0);

    int u = 0;
    for (; u < NT - 2; ++u) KGROUP(true, VM6);
    KGROUP(false, VM0);
    ++u;
    KGROUP(false, (void)0);

    // epilogue
    const int r0 = bm0 + wm * 64 + kl * 4;
    const int c0g = bn0 + wn * 64 + l15;
#pragma unroll
    for (int i = 0; i < 4; ++i) {
#pragma unroll
        for (int j = 0; j < 4; ++j) {
            int col = c0g + j * 16;
#pragma unroll
            for (int r = 0; r < 4; ++r) {
                int row = r0 + i * 16 + r;
                float v = acc[i][j][r];
                if constexpr (EPI == 0) {
                    ((unsigned short*)Cout)[(size_t)row * ldc + col] = f2b(v);
                } else if constexpr (EPI == 1) {
                    ((float*)Cout)[(size_t)row * ldc + col] = v;
                } else if constexpr (EPI == 2) {
                    v += bias[col];
                    float t = tanhf(0.7978845608f * (v + 0.044715f * v * v * v));
                    ((unsigned short*)Cout)[(size_t)row * ldc + col] = f2b(0.5f * v * (1.0f + t));
                } else {
                    v += bias[col] + addm[(size_t)row * ldc + col];
                    ((float*)Cout)[(size_t)row * ldc + col] = v;
                }
            }
        }
    }
}

// ---------------- flash attention ----------------
__global__ __launch_bounds__(256, 2) void attn_kernel(const unsigned short* __restrict__ qkv,
                                                      const unsigned short* __restrict__ vT,
                                                      const float* __restrict__ bias,
                                                      unsigned short* __restrict__ attn_vec) {
    __shared__ unsigned short kL[64 * 264];
    __shared__ unsigned short vL[256 * 72];
    __shared__ unsigned short pL[4][16 * 72];

    int qb = blockIdx.x, head = blockIdx.y;
    int tid = threadIdx.x, lane = tid & 63, wave = tid >> 6;
    int q16 = lane & 15, q4 = lane >> 4;

    short8 qf[8];
    {
        const unsigned short* qp =
            qkv + (size_t)(qb * 64 + wave * 16 + q16) * (3 * DM) + head * DHEAD + (q4 << 3);
#pragma unroll
        for (int kk = 0; kk < 8; ++kk) qf[kk] = *(const short8*)(qp + kk * 32);
    }

    f32x4 o[16];
#pragma unroll
    for (int d = 0; d < 16; ++d) o[d] = (f32x4){0.f, 0.f, 0.f, 0.f};
    float m_run[4] = {-INFINITY, -INFINITY, -INFINITY, -INFINITY};
    float l_run[4] = {0.f, 0.f, 0.f, 0.f};
    int qrow0 = qb * 64 + wave * 16 + q4 * 4;

    for (int t = 0; t <= qb; ++t) {
        int kv0 = t * 64;
#pragma unroll
        for (int rr = 0; rr < 8; ++rr) {
            int i = tid + rr * 256;
            int row = i >> 5, c8 = (i & 31) << 3;
            *(ushort8v*)(kL + row * 264 + c8) =
                *(const ushort8v*)(qkv + (size_t)(kv0 + row) * (3 * DM) + DM + head * DHEAD + c8);
        }
#pragma unroll
        for (int rr = 0; rr < 8; ++rr) {
            int i = tid + rr * 256;
            int d = i >> 3, c8 = (i & 7) << 3;
            *(ushort8v*)(vL + d * 72 + c8) =
                *(const ushort8v*)(vT + (size_t)(head * DHEAD + d) * SEQ + kv0 + c8);
        }
        __syncthreads();

        f32x4 s[4];
#pragma unroll
        for (int c = 0; c < 4; ++c) s[c] = (f32x4){0.f, 0.f, 0.f, 0.f};
#pragma unroll
        for (int kk = 0; kk < 8; ++kk) {
#pragma unroll
            for (int c = 0; c < 4; ++c) {
                short8 kf = *(const short8*)(kL + (c * 16 + q16) * 264 + kk * 32 + (q4 << 3));
                s[c] = __builtin_amdgcn_mfma_f32_16x16x32_bf16(qf[kk], kf, s[c], 0, 0, 0);
            }
        }

        bool diag = (t == qb);
#pragma unroll
        for (int r = 0; r < 4; ++r) {
            int qr = qrow0 + r;
            float sv[4];
#pragma unroll
            for (int c = 0; c < 4; ++c) {
                float vv = s[c][r] * 0.0625f + bias[(size_t)qr * SEQ + kv0 + c * 16 + q16];
                if (diag && (kv0 + c * 16 + q16) > qr) vv = -1e30f;
                sv[c] = vv;
            }
            float m = fmaxf(fmaxf(sv[0], sv[1]), fmaxf(sv[2], sv[3]));
#pragma unroll
            for (int off = 1; off < 16; off <<= 1) m = fmaxf(m, __shfl_xor(m, off));
            float mn = fmaxf(m_run[r], m);
            float alpha = __expf(m_run[r] - mn);
            float psum = 0.f;
#pragma unroll
            for (int c = 0; c < 4; ++c) {
                float p = __expf(sv[c] - mn);
                psum += p;
                pL[wave][(q4 * 4 + r) * 72 + c * 16 + q16] = f2b(p);
            }
#pragma unroll
            for (int off = 1; off < 16; off <<= 1) psum += __shfl_xor(psum, off);
            l_run[r] = l_run[r] * alpha + psum;
            m_run[r] = mn;
#pragma unroll
            for (int d = 0; d < 16; ++d) o[d][r] *= alpha;
        }

#pragma unroll
        for (int ks = 0; ks < 2; ++ks) {
            short8 pa = *(const short8*)(pL[wave] + q16 * 72 + ks * 32 + (q4 << 3));
#pragma unroll
            for (int d = 0; d < 16; ++d) {
                short8 vb = *(const short8*)(vL + (d * 16 + q16) * 72 + ks * 32 + (q4 << 3));
                o[d] = __builtin_amdgcn_mfma_f32_16x16x32_bf16(pa, vb, o[d], 0, 0, 0);
            }
        }
        __syncthreads();
    }

#pragma unroll
    for (int r = 0; r < 4; ++r) {
        float inv = 1.0f / l_run[r];
#pragma unroll
        for (int d = 0; d < 16; ++d)
            attn_vec[(size_t)(qrow0 + r) * DM + head * DHEAD + d * 16 + q16] = f2b(o[d][r] * inv);
    }
}

// ---------------- launch ----------------
extern "C" void kernel_launch(void* const* d_in, const int* in_sizes, int n_in,
                              void* d_out, int out_size, void* d_ws, size_t ws_size,
                              hipStream_t stream) {
    const float* x = (const float*)d_in[0];
    const float* attn_bias = (const float*)d_in[1];
    const float* ln_scale = (const float*)d_in[2];
    const float* ln_offset = (const float*)d_in[3];
    const float* wq = (const float*)d_in[4];
    const float* wk = (const float*)d_in[5];
    const float* wv = (const float*)d_in[6];
    const float* wo = (const float*)d_in[7];
    const float* w_ffn = (const float*)d_in[8];
    const float* b_ffn = (const float*)d_in[9];
    const float* w_ffn_o = (const float*)d_in[10];
    const float* b_ffn_o = (const float*)d_in[11];
    float* out = (float*)d_out;

    char* p = (char*)d_ws;
    unsigned short* WT_qkv = (unsigned short*)p; p += (size_t)3 * DM * DM * 2;
    unsigned short* WT_o = (unsigned short*)p;   p += (size_t)DM * DM * 2;
    unsigned short* WT_f1 = (unsigned short*)p;  p += (size_t)DFF * DM * 2;
    unsigned short* WT_f2 = (unsigned short*)p;  p += (size_t)DM * DFF * 2;
    unsigned short* hB = (unsigned short*)p;     p += (size_t)SEQ * DM * 2;
    unsigned short* qkvB = (unsigned short*)p;   p += (size_t)SEQ * 3 * DM * 2;
    unsigned short* vTB = (unsigned short*)p;    p += (size_t)DM * SEQ * 2;
    unsigned short* avB = (unsigned short*)p;    p += (size_t)SEQ * DM * 2;
    float* attn_out = (float*)p;                 p += (size_t)SEQ * DM * 4;
    unsigned short* ffB = (unsigned short*)p;    p += (size_t)SEQ * DFF * 2;

    transpose_cvt<float><<<dim3(DM / 64, DM / 64), 256, 0, stream>>>(wq, WT_qkv, DM, DM, DM, DM);
    transpose_cvt<float><<<dim3(DM / 64, DM / 64), 256, 0, stream>>>(wk, WT_qkv + (size_t)DM * DM, DM, DM, DM, DM);
    transpose_cvt<float><<<dim3(DM / 64, DM / 64), 256, 0, stream>>>(wv, WT_qkv + (size_t)2 * DM * DM, DM, DM, DM, DM);
    transpose_cvt<float><<<dim3(DM / 64, DM / 64), 256, 0, stream>>>(wo, WT_o, DM, DM, DM, DM);
    transpose_cvt<float><<<dim3(DFF / 64, DM / 64), 256, 0, stream>>>(w_ffn, WT_f1, DFF, DM, DM, DFF);
    transpose_cvt<float><<<dim3(DM / 64, DFF / 64), 256, 0, stream>>>(w_ffn_o, WT_f2, DM, DFF, DFF, DM);

    ln_kernel<<<SEQ, 256, 0, stream>>>(x, ln_scale, ln_offset, hB);

    // QKV: M=2048, N=12288, K=4096 -> 8*96 = 768 blocks
    gemm256<0><<<(SEQ / 256) * (3 * DM / 128), 512, 0, stream>>>(hB, WT_qkv, qkvB, SEQ, 3 * DM, DM, 3 * DM, nullptr, nullptr);
    transpose_cvt<unsigned short><<<dim3(DM / 64, SEQ / 64), 256, 0, stream>>>(qkvB + 2 * DM, vTB, 3 * DM, SEQ, SEQ, DM);

    attn_kernel<<<dim3(SEQ / 64, NHEADS), 256, 0, stream>>>(qkvB, vTB, attn_bias, avB);

    // WO: 8*32 = 256 blocks
    gemm256<1><<<(SEQ / 256) * (DM / 128), 512, 0, stream>>>(avB, WT_o, attn_out, SEQ, DM, DM, DM, nullptr, nullptr);
    // FFN1: 8*128 = 1024 blocks
    gemm256<2><<<(SEQ / 256) * (DFF / 128), 512, 0, stream>>>(hB, WT_f1, ffB, SEQ, DFF, DM, DFF, b_ffn, nullptr);
    // FFN2: 8*32 = 256 blocks
    gemm256<3><<<(SEQ / 256) * (DM / 128), 512, 0, stream>>>(ffB, WT_f2, out, SEQ, DM, DFF, DM, b_ffn_o, attn_out);
}